// Round 1
// baseline (368.575 us; speedup 1.0000x reference)
//
#include <hip/hip_runtime.h>
#include <hip/hip_bf16.h>

#define BATCH   256
#define NLAYERS 32
#define HID     1024
#define INTER   2816
#define BK      64

typedef __attribute__((ext_vector_type(8))) short bf16x8;
typedef __attribute__((ext_vector_type(4))) float f32x4;
typedef __attribute__((ext_vector_type(4))) int   i32x4;

__device__ __forceinline__ ushort f2bf(float f) {
  union { float f; unsigned u; } v; v.f = f;
  unsigned u = v.u;
  u += 0x7FFFu + ((u >> 16) & 1u);   // round-to-nearest-even
  return (ushort)(u >> 16);
}

__device__ __forceinline__ void cvt_store8(ushort* dst, f32x4 a, f32x4 b) {
  bf16x8 o;
  o[0] = (short)f2bf(a[0]); o[1] = (short)f2bf(a[1]);
  o[2] = (short)f2bf(a[2]); o[3] = (short)f2bf(a[3]);
  o[4] = (short)f2bf(b[0]); o[5] = (short)f2bf(b[1]);
  o[6] = (short)f2bf(b[2]); o[7] = (short)f2bf(b[3]);
  *(bf16x8*)dst = o;
}

// ---------------------------------------------------------------------------
// Kernel 1: act[layer][b][i] = silu(X Wg^T) * (X Wu^T), bf16 output to ws.
// BM=256 (full batch -> each weight element read from HBM exactly once),
// BN=64 (gate+up fused, so Wg and Wu tiles each staged once), BK=64.
// 8 waves as 4(M)x2(N): per-wave 64x32 of gate AND up; 16x16x32 bf16 MFMA.
// LDS tiles XOR-swizzled: u ^= (row&7)<<3 (in ushort units) to kill the
// 128B-row-stride bank conflict on ds_read_b128.
// ---------------------------------------------------------------------------
__global__ __launch_bounds__(512) void k_gateup(
    const float* __restrict__ h, const float* __restrict__ Wg,
    const float* __restrict__ Wu, ushort* __restrict__ act) {
  const int bid   = blockIdx.x;
  const int layer = bid / (INTER / 64);
  const int itile = bid % (INTER / 64);
  const int i0    = itile * 64;
  const int tid   = threadIdx.x;
  const int lane  = tid & 63;
  const int wave  = tid >> 6;
  const int wm    = wave >> 1;   // 0..3  (M block of 64 rows)
  const int wn    = wave & 1;    // 0..1  (N block of 32 cols)

  __shared__ ushort lds[BATCH * BK + 2 * 64 * BK];   // 48 KiB
  ushort* Xl = lds;
  ushort* Gl = lds + BATCH * BK;
  ushort* Ul = Gl + 64 * BK;

  f32x4 ag[4][2] = {};
  f32x4 au[4][2] = {};

  // ---- per-thread staging geometry (fixed row/kc, advance by BK per step)
  // X: 2048 granules of 8 floats; 4 per thread.
  int xrow[4], xkc[4], xldst[4];
  const float* xsrc[4];
#pragma unroll
  for (int r = 0; r < 4; ++r) {
    int g = tid + 512 * r;
    xrow[r] = g >> 3;
    xkc[r]  = g & 7;
    xldst[r] = xrow[r] * BK + ((xkc[r] ^ (xrow[r] & 7)) << 3);
    xsrc[r] = h + (size_t)xrow[r] * (NLAYERS * HID) + (size_t)layer * HID + xkc[r] * 8;
  }
  const int wrow = tid >> 3, wkc = tid & 7;
  const int wldst = wrow * BK + ((wkc ^ (wrow & 7)) << 3);
  const float* gsrc = Wg + (size_t)layer * INTER * HID + (size_t)(i0 + wrow) * HID + wkc * 8;
  const float* usrc = Wu + (size_t)layer * INTER * HID + (size_t)(i0 + wrow) * HID + wkc * 8;

  f32x4 rx[4][2], rg[2], ru[2];

  // prologue: issue k=0 loads
#pragma unroll
  for (int r = 0; r < 4; ++r) { rx[r][0] = *(const f32x4*)xsrc[r]; rx[r][1] = *(const f32x4*)(xsrc[r] + 4); }
  rg[0] = *(const f32x4*)gsrc; rg[1] = *(const f32x4*)(gsrc + 4);
  ru[0] = *(const f32x4*)usrc; ru[1] = *(const f32x4*)(usrc + 4);

  const int NK = HID / BK;   // 16
  for (int k = 0; k < NK; ++k) {
    __syncthreads();                                  // prev compute done
#pragma unroll
    for (int r = 0; r < 4; ++r) cvt_store8(&Xl[xldst[r]], rx[r][0], rx[r][1]);
    cvt_store8(&Gl[wldst], rg[0], rg[1]);
    cvt_store8(&Ul[wldst], ru[0], ru[1]);
    __syncthreads();                                  // LDS ready

    if (k + 1 < NK) {                                 // prefetch next step
      int off = (k + 1) * BK;
#pragma unroll
      for (int r = 0; r < 4; ++r) {
        rx[r][0] = *(const f32x4*)(xsrc[r] + off);
        rx[r][1] = *(const f32x4*)(xsrc[r] + off + 4);
      }
      rg[0] = *(const f32x4*)(gsrc + off); rg[1] = *(const f32x4*)(gsrc + off + 4);
      ru[0] = *(const f32x4*)(usrc + off); ru[1] = *(const f32x4*)(usrc + off + 4);
    }

    // compute on current LDS tile: 2 k-substeps of 32
#pragma unroll
    for (int ks = 0; ks < 2; ++ks) {
      const int kg = ks * 4 + (lane >> 4);            // 16B granule index 0..7
      bf16x8 af[4];
#pragma unroll
      for (int m = 0; m < 4; ++m) {
        int row = wm * 64 + m * 16 + (lane & 15);
        af[m] = *(bf16x8*)&Xl[row * BK + ((kg ^ (row & 7)) << 3)];
      }
#pragma unroll
      for (int n = 0; n < 2; ++n) {
        int row = wn * 32 + n * 16 + (lane & 15);
        int u   = row * BK + ((kg ^ (row & 7)) << 3);
        bf16x8 bg = *(bf16x8*)&Gl[u];
        bf16x8 bu = *(bf16x8*)&Ul[u];
#pragma unroll
        for (int m = 0; m < 4; ++m) {
          ag[m][n] = __builtin_amdgcn_mfma_f32_16x16x32_bf16(af[m], bg, ag[m][n], 0, 0, 0);
          au[m][n] = __builtin_amdgcn_mfma_f32_16x16x32_bf16(af[m], bu, au[m][n], 0, 0, 0);
        }
      }
    }
  }

  // epilogue: silu(gate)*up -> bf16 act.  C/D map: col=lane&15, row=(lane>>4)*4+r
  const int c16 = lane & 15;
  const int r4  = (lane >> 4) * 4;
#pragma unroll
  for (int m = 0; m < 4; ++m)
#pragma unroll
    for (int n = 0; n < 2; ++n)
#pragma unroll
      for (int r = 0; r < 4; ++r) {
        float g = ag[m][n][r];
        float u = au[m][n][r];
        float a = (g / (1.f + __expf(-g))) * u;
        int b = wm * 64 + m * 16 + r4 + r;
        int i = i0 + wn * 32 + n * 16 + c16;
        act[((size_t)layer * BATCH + b) * INTER + i] = f2bf(a);
      }
}

// ---------------------------------------------------------------------------
// Kernel 2: out[b][layer][d] = act Wd^T.  M=256, N=1024 (BN=64), K=2816.
// act is already bf16 (no conversion); Wd converted fp32->bf16 in-flight.
// ---------------------------------------------------------------------------
__global__ __launch_bounds__(512) void k_down(
    const ushort* __restrict__ act, const float* __restrict__ Wd,
    float* __restrict__ out) {
  const int bid   = blockIdx.x;
  const int layer = bid / (HID / 64);
  const int dtile = bid % (HID / 64);
  const int d0    = dtile * 64;
  const int tid   = threadIdx.x;
  const int lane  = tid & 63;
  const int wave  = tid >> 6;
  const int wm    = wave >> 1;
  const int wn    = wave & 1;

  __shared__ ushort lds[BATCH * BK + 64 * BK];       // 40 KiB
  ushort* Al = lds;
  ushort* Wl = lds + BATCH * BK;

  f32x4 acc[4][2] = {};

  int arow[4], akc[4], aldst[4];
  const ushort* asrc[4];
#pragma unroll
  for (int r = 0; r < 4; ++r) {
    int g = tid + 512 * r;
    arow[r] = g >> 3;
    akc[r]  = g & 7;
    aldst[r] = arow[r] * BK + ((akc[r] ^ (arow[r] & 7)) << 3);
    asrc[r] = act + ((size_t)layer * BATCH + arow[r]) * INTER + akc[r] * 8;
  }
  const int wrow = tid >> 3, wkc = tid & 7;
  const int wldst = wrow * BK + ((wkc ^ (wrow & 7)) << 3);
  const float* wsrc = Wd + (size_t)layer * HID * INTER + (size_t)(d0 + wrow) * INTER + wkc * 8;

  i32x4 ra[4];
  f32x4 rw[2];

#pragma unroll
  for (int r = 0; r < 4; ++r) ra[r] = *(const i32x4*)asrc[r];
  rw[0] = *(const f32x4*)wsrc; rw[1] = *(const f32x4*)(wsrc + 4);

  const int NK = INTER / BK;   // 44
  for (int k = 0; k < NK; ++k) {
    __syncthreads();
#pragma unroll
    for (int r = 0; r < 4; ++r) *(i32x4*)&Al[aldst[r]] = ra[r];
    cvt_store8(&Wl[wldst], rw[0], rw[1]);
    __syncthreads();

    if (k + 1 < NK) {
      int off = (k + 1) * BK;
#pragma unroll
      for (int r = 0; r < 4; ++r) ra[r] = *(const i32x4*)(asrc[r] + off);
      rw[0] = *(const f32x4*)(wsrc + off); rw[1] = *(const f32x4*)(wsrc + off + 4);
    }

#pragma unroll
    for (int ks = 0; ks < 2; ++ks) {
      const int kg = ks * 4 + (lane >> 4);
      bf16x8 af[4];
#pragma unroll
      for (int m = 0; m < 4; ++m) {
        int row = wm * 64 + m * 16 + (lane & 15);
        af[m] = *(bf16x8*)&Al[row * BK + ((kg ^ (row & 7)) << 3)];
      }
#pragma unroll
      for (int n = 0; n < 2; ++n) {
        int row = wn * 32 + n * 16 + (lane & 15);
        bf16x8 bw = *(bf16x8*)&Wl[row * BK + ((kg ^ (row & 7)) << 3)];
#pragma unroll
        for (int m = 0; m < 4; ++m)
          acc[m][n] = __builtin_amdgcn_mfma_f32_16x16x32_bf16(af[m], bw, acc[m][n], 0, 0, 0);
      }
    }
  }

  const int c16 = lane & 15;
  const int r4  = (lane >> 4) * 4;
#pragma unroll
  for (int m = 0; m < 4; ++m)
#pragma unroll
    for (int n = 0; n < 2; ++n)
#pragma unroll
      for (int r = 0; r < 4; ++r) {
        int b = wm * 64 + m * 16 + r4 + r;
        int d = d0 + wn * 32 + n * 16 + c16;
        out[(size_t)b * (NLAYERS * HID) + (size_t)layer * HID + d] = acc[m][n][r];
      }
}

extern "C" void kernel_launch(void* const* d_in, const int* in_sizes, int n_in,
                              void* d_out, int out_size, void* d_ws, size_t ws_size,
                              hipStream_t stream) {
  const float* h  = (const float*)d_in[0];
  const float* Wg = (const float*)d_in[1];
  const float* Wu = (const float*)d_in[2];
  const float* Wd = (const float*)d_in[3];
  float* out  = (float*)d_out;
  ushort* act = (ushort*)d_ws;   // 32*256*2816*2 = 46.1 MB of scratch

  hipLaunchKernelGGL(k_gateup, dim3(NLAYERS * (INTER / 64)), dim3(512), 0, stream,
                     h, Wg, Wu, act);
  hipLaunchKernelGGL(k_down, dim3(NLAYERS * (HID / 64)), dim3(512), 0, stream,
                     act, Wd, out);
}